// Round 7
// baseline (545.982 us; speedup 1.0000x reference)
//
#include <hip/hip_runtime.h>

#define N_NODES 100000
#define N_EDGES 1600000
#define SLICE 12500      // N_NODES/8 dst-slice per group
#define CAP   204800     // per-slice pair capacity (200k expected + 11 sigma slack)
#define ACHUNK 2048      // edges per bucket block
#define NACH  782        // ceil(N_EDGES / ACHUNK)
#define HCHUNK 8192      // pairs per hist/fill chunk
#define NHCH  25         // CAP / HCHUNK

typedef _Float16 f16;
typedef _Float16 f16x2 __attribute__((ext_vector_type(2)));
typedef _Float16 f16x4 __attribute__((ext_vector_type(4)));
typedef _Float16 f16x8 __attribute__((ext_vector_type(8)));
typedef float f32x4 __attribute__((ext_vector_type(4)));

// ---------------- phase A: bucket edges by dst-slice (SoA) + fused x->fp16 cvt ----------------
__global__ void bucket_cvt_kernel(const int* __restrict__ ei,
                                  int* __restrict__ bsrc, int* __restrict__ bdst,
                                  int* __restrict__ scur,
                                  const float* __restrict__ x, f16* __restrict__ x16) {
  __shared__ int lcnt[8];
  __shared__ int lbase[8];
  int b = blockIdx.x;
  if (b < NACH) {
    if (threadIdx.x < 8) lcnt[threadIdx.x] = 0;
    __syncthreads();
    int base = b * ACHUNK;
    int msrc[8], mdst[8], mrank[8], msl[8];
    #pragma unroll
    for (int j = 0; j < 8; ++j) {
      int i = base + j * 256 + threadIdx.x;
      msl[j] = -1;
      if (i < N_EDGES) {
        msrc[j] = ei[i];
        int d = ei[N_EDGES + i];
        mdst[j] = d;
        int sl = d / SLICE;  // 0..7
        msl[j] = sl;
        mrank[j] = atomicAdd(&lcnt[sl], 1);  // LDS atomic
      }
    }
    __syncthreads();
    if (threadIdx.x < 8) lbase[threadIdx.x] = atomicAdd(&scur[threadIdx.x], lcnt[threadIdx.x]);
    __syncthreads();
    #pragma unroll
    for (int j = 0; j < 8; ++j) {
      if (msl[j] >= 0) {
        size_t o = (size_t)msl[j] * CAP + lbase[msl[j]] + mrank[j];
        bsrc[o] = msrc[j];
        bdst[o] = mdst[j];
      }
    }
  } else {
    int i = ((b - NACH) * 256 + threadIdx.x) * 16;  // 16 floats/thread
    float4 a0 = *(const float4*)(x + i);
    float4 a1 = *(const float4*)(x + i + 4);
    float4 a2 = *(const float4*)(x + i + 8);
    float4 a3 = *(const float4*)(x + i + 12);
    f16x8 v0 = {(f16)a0.x, (f16)a0.y, (f16)a0.z, (f16)a0.w,
                (f16)a1.x, (f16)a1.y, (f16)a1.z, (f16)a1.w};
    f16x8 v1 = {(f16)a2.x, (f16)a2.y, (f16)a2.z, (f16)a2.w,
                (f16)a3.x, (f16)a3.y, (f16)a3.z, (f16)a3.w};
    *(f16x8*)(x16 + i) = v0;
    *(f16x8*)(x16 + i + 8) = v1;
  }
}

// ---------------- phase B: hist from slice-grouped dsts (XCD-local atomics, 1x read) ----------------
__global__ void hist2_kernel(const int* __restrict__ bdst, const int* __restrict__ scur,
                             int* __restrict__ counts) {
  int grp = blockIdx.x & 7;
  int cnt = scur[grp];
  int base = (blockIdx.x >> 3) * HCHUNK;
  const int* p = bdst + (size_t)grp * CAP;
  for (int k = threadIdx.x; k < HCHUNK; k += 256) {
    int i = base + k;
    if (i < cnt) atomicAdd(&counts[p[i]], 1);
  }
}

__global__ void scan1_kernel(const int* __restrict__ counts, int* __restrict__ offs,
                             int* __restrict__ bsums, int n) {
  __shared__ int sd[256];
  int t = threadIdx.x;
  int base = blockIdx.x * 1024 + t * 4;
  int v0 = (base + 0 < n) ? counts[base + 0] : 0;
  int v1 = (base + 1 < n) ? counts[base + 1] : 0;
  int v2 = (base + 2 < n) ? counts[base + 2] : 0;
  int v3 = (base + 3 < n) ? counts[base + 3] : 0;
  int s = v0 + v1 + v2 + v3;
  sd[t] = s;
  __syncthreads();
  for (int off = 1; off < 256; off <<= 1) {
    int x = (t >= off) ? sd[t - off] : 0;
    __syncthreads();
    sd[t] += x;
    __syncthreads();
  }
  int excl = sd[t] - s;
  if (t == 255) bsums[blockIdx.x] = sd[255];
  int r = excl;
  if (base + 0 < n) offs[base + 0] = r; r += v0;
  if (base + 1 < n) offs[base + 1] = r; r += v1;
  if (base + 2 < n) offs[base + 2] = r; r += v2;
  if (base + 3 < n) offs[base + 3] = r;
}

__global__ void scan2_kernel(int* __restrict__ bsums, int nb) {
  __shared__ int sd[128];
  int t = threadIdx.x;
  int v = (t < nb) ? bsums[t] : 0;
  sd[t] = v;
  __syncthreads();
  for (int off = 1; off < 128; off <<= 1) {
    int x = (t >= off) ? sd[t - off] : 0;
    __syncthreads();
    sd[t] += x;
    __syncthreads();
  }
  if (t < nb) bsums[t] = sd[t] - v;  // exclusive
}

__global__ void scan3_kernel(int* __restrict__ offs, const int* __restrict__ bsums, int n) {
  int i = blockIdx.x * blockDim.x + threadIdx.x;
  if (i < n) offs[i] += bsums[i >> 10];
}

// ---------------- phase C: fill from slice-grouped pairs (XCD-local cursors, 1x read) ----------------
__global__ void fill2_kernel(const int* __restrict__ bsrc, const int* __restrict__ bdst,
                             const int* __restrict__ scur, const int* __restrict__ offs,
                             int* __restrict__ cursors, int* __restrict__ srcs) {
  int grp = blockIdx.x & 7;
  int cnt = scur[grp];
  int base = (blockIdx.x >> 3) * HCHUNK;
  size_t go = (size_t)grp * CAP;
  for (int k = threadIdx.x; k < HCHUNK; k += 256) {
    int i = base + k;
    if (i < cnt) {
      int d = bdst[go + i];
      int pos = offs[d] + atomicAdd(&cursors[d], 1);
      srcs[pos] = bsrc[go + i];
    }
  }
}

// ---------------- weight prep ----------------
// Wt[c*128 + kc*8 + j] = (f16)W[((kc ^ (c&7))*8 + j)*128 + c]
struct WPack { const float* w[6]; f16* o[6]; };
__global__ void wprep_all_kernel(WPack p) {
  int wi = blockIdx.x >> 6;
  int t = (blockIdx.x & 63) * 256 + threadIdx.x;
  int c = t >> 7;
  int i = t & 127;
  int kc = i >> 3, j = i & 7;
  int k = ((kc ^ (c & 7)) << 3) + j;
  p.o[wi][t] = (f16)p.w[wi][k * 128 + c];
}

// ---------------- aggregation: z[i] = h[i] + sum_{j in N_in(i)} h[j] ----------------
// 16-lane group per node: 16 lanes x f16x8 = full 256B row; 4 nodes per wave.
__global__ void aggregate_kernel(const f16* __restrict__ h, const int* __restrict__ offs,
                                 const int* __restrict__ deg, const int* __restrict__ srcs,
                                 f16* __restrict__ z, int n) {
  int gid = (int)((blockIdx.x * blockDim.x + threadIdx.x) >> 4);
  int gl = threadIdx.x & 15;
  int lb = threadIdx.x & 48;  // group base lane within wave
  if (gid >= n) return;
  int beg = offs[gid];
  int d = deg[gid];
  f16x8 hv = *(const f16x8*)(h + (size_t)gid * 128 + gl * 8);
  float acc[8];
  #pragma unroll
  for (int q = 0; q < 8; ++q) acc[q] = (float)hv[q];
  for (int base = 0; base < d; base += 16) {
    int cnt = min(16, d - base);
    int sv = (base + gl < d) ? srcs[beg + base + gl] : 0;
    int j = 0;
    for (; j + 2 <= cnt; j += 2) {
      int s0 = __shfl(sv, lb + j);
      int s1 = __shfl(sv, lb + j + 1);
      f16x8 a0 = *(const f16x8*)(h + (size_t)s0 * 128 + gl * 8);
      f16x8 a1 = *(const f16x8*)(h + (size_t)s1 * 128 + gl * 8);
      #pragma unroll
      for (int q = 0; q < 8; ++q) acc[q] += (float)a0[q] + (float)a1[q];
    }
    for (; j < cnt; ++j) {
      int s = __shfl(sv, lb + j);
      f16x8 a = *(const f16x8*)(h + (size_t)s * 128 + gl * 8);
      #pragma unroll
      for (int q = 0; q < 8; ++q) acc[q] += (float)a[q];
    }
  }
  f16x8 o;
  #pragma unroll
  for (int q = 0; q < 8; ++q) o[q] = (f16)acc[q];
  *(f16x8*)(z + (size_t)gid * 128 + gl * 8) = o;
}

// ---------------- fused GIN layer (swapped-MFMA): h2 = relu(relu(A@W1+b1)@W2+b2) ----------------
template <int FUSE>
__global__ __launch_bounds__(256, 2)
void layer_kernel(const f16* __restrict__ A, const f16* __restrict__ W1t,
                  const f16* __restrict__ W2t,
                  const float* __restrict__ bias1, const float* __restrict__ bias2,
                  void* __restrict__ outv,
                  const float* __restrict__ wout, const float* __restrict__ bout, int n) {
  __shared__ f16 Az[128 * 128];  // 32KB
  __shared__ f16 Ws[128 * 128];  // 32KB
  const int t = threadIdx.x;
  const int lane = t & 63;
  const int w = t >> 6;
  const int rowBase = blockIdx.x * 128;
  const int wr = w >> 1, wc = w & 1;
  const int ls = lane & 15, lg = lane >> 4;

  // ---- stage A (swizzled) + W1 (linear; pre-swizzled in global) ----
  {
    const char* Ab = (const char*)(A + (size_t)rowBase * 128);
    float4 va[8], v1[8];
    #pragma unroll
    for (int i = 0; i < 8; ++i) {
      int s = w * 512 + i * 64 + lane;
      va[i] = *(const float4*)(Ab + s * 16);
      v1[i] = *(const float4*)((const char*)W1t + s * 16);
    }
    #pragma unroll
    for (int i = 0; i < 8; ++i) {
      int s = w * 512 + i * 64 + lane;
      int r = s >> 4, c = s & 15;
      *(float4*)((char*)Az + r * 256 + ((c ^ (r & 7)) << 4)) = va[i];
      *(float4*)((char*)Ws + s * 16) = v1[i];
    }
  }
  // prefetch W2 into regs (consumed after phase 1)
  float4 v2[8];
  #pragma unroll
  for (int i = 0; i < 8; ++i) {
    int s = w * 512 + i * 64 + lane;
    v2[i] = *(const float4*)((const char*)W2t + s * 16);
  }
  __syncthreads();

  f32x4 acc[4][4];
  #pragma unroll
  for (int m = 0; m < 4; ++m)
    #pragma unroll
    for (int nn = 0; nn < 4; ++nn)
      acc[m][nn] = (f32x4){0.f, 0.f, 0.f, 0.f};

  // ---- phase 1: acc[m][nn] = h1^T fragment ----
  #pragma unroll
  for (int ks = 0; ks < 4; ++ks) {
    f16x8 wf[4], af[4];
    #pragma unroll
    for (int m = 0; m < 4; ++m) {
      int c = wr * 64 + m * 16 + ls;
      int ch = (ks * 4 + lg) ^ (c & 7);
      wf[m] = *(const f16x8*)((const char*)Ws + c * 256 + (ch << 4));
    }
    #pragma unroll
    for (int nn = 0; nn < 4; ++nn) {
      int r = wc * 64 + nn * 16 + ls;
      int ch = (ks * 4 + lg) ^ (r & 7);
      af[nn] = *(const f16x8*)((const char*)Az + r * 256 + (ch << 4));
    }
    #pragma unroll
    for (int m = 0; m < 4; ++m)
      #pragma unroll
      for (int nn = 0; nn < 4; ++nn)
        acc[m][nn] = __builtin_amdgcn_mfma_f32_16x16x32_f16(wf[m], af[nn], acc[m][nn], 0, 0, 0);
  }
  __syncthreads();  // all phase-1 LDS reads complete

  // ---- W2 -> Ws ; h1 (relu+bias) -> Az as packed b64 ----
  #pragma unroll
  for (int i = 0; i < 8; ++i) {
    int s = w * 512 + i * 64 + lane;
    *(float4*)((char*)Ws + s * 16) = v2[i];
  }
  #pragma unroll
  for (int m = 0; m < 4; ++m) {
    int c = wr * 64 + m * 16 + lg * 4;
    float b0 = bias1[c + 0], b1v = bias1[c + 1], b2v_ = bias1[c + 2], b3 = bias1[c + 3];
    #pragma unroll
    for (int nn = 0; nn < 4; ++nn) {
      int r = wc * 64 + nn * 16 + ls;
      f16x4 pv = {(f16)fmaxf(acc[m][nn][0] + b0, 0.f),
                  (f16)fmaxf(acc[m][nn][1] + b1v, 0.f),
                  (f16)fmaxf(acc[m][nn][2] + b2v_, 0.f),
                  (f16)fmaxf(acc[m][nn][3] + b3, 0.f)};
      *(f16x4*)((char*)Az + r * 256 + ((((c >> 3)) ^ (r & 7)) << 4) + (c & 7) * 2) = pv;
    }
  }
  __syncthreads();

  // ---- phase 2: acc[m][nn] = h2^T fragment ----
  #pragma unroll
  for (int m = 0; m < 4; ++m)
    #pragma unroll
    for (int nn = 0; nn < 4; ++nn)
      acc[m][nn] = (f32x4){0.f, 0.f, 0.f, 0.f};
  #pragma unroll
  for (int ks = 0; ks < 4; ++ks) {
    f16x8 wf[4], hf[4];
    #pragma unroll
    for (int m = 0; m < 4; ++m) {
      int c = wr * 64 + m * 16 + ls;
      int ch = (ks * 4 + lg) ^ (c & 7);
      wf[m] = *(const f16x8*)((const char*)Ws + c * 256 + (ch << 4));
    }
    #pragma unroll
    for (int nn = 0; nn < 4; ++nn) {
      int r = wc * 64 + nn * 16 + ls;
      int ch = (ks * 4 + lg) ^ (r & 7);
      hf[nn] = *(const f16x8*)((const char*)Az + r * 256 + (ch << 4));
    }
    #pragma unroll
    for (int m = 0; m < 4; ++m)
      #pragma unroll
      for (int nn = 0; nn < 4; ++nn)
        acc[m][nn] = __builtin_amdgcn_mfma_f32_16x16x32_f16(wf[m], hf[nn], acc[m][nn], 0, 0, 0);
  }

  if (FUSE) {
    float s_[4] = {0.f, 0.f, 0.f, 0.f};
    #pragma unroll
    for (int m = 0; m < 4; ++m) {
      int c = wr * 64 + m * 16 + lg * 4;
      float bb[4], wv[4];
      #pragma unroll
      for (int i = 0; i < 4; ++i) { bb[i] = bias2[c + i]; wv[i] = wout[c + i]; }
      #pragma unroll
      for (int nn = 0; nn < 4; ++nn)
        #pragma unroll
        for (int i = 0; i < 4; ++i)
          s_[nn] += fmaxf(acc[m][nn][i] + bb[i], 0.f) * wv[i];
    }
    #pragma unroll
    for (int nn = 0; nn < 4; ++nn) {
      s_[nn] += __shfl_xor(s_[nn], 16);
      s_[nn] += __shfl_xor(s_[nn], 32);
    }
    __syncthreads();
    float* red = (float*)Az;  // [128][2]
    if (lg == 0) {
      #pragma unroll
      for (int nn = 0; nn < 4; ++nn) red[(wc * 64 + nn * 16 + ls) * 2 + wr] = s_[nn];
    }
    __syncthreads();
    if (t < 128) {
      int gr = rowBase + t;
      if (gr < n) ((float*)outv)[gr] = red[t * 2] + red[t * 2 + 1] + bout[0];
    }
  } else {
    __syncthreads();  // phase-2 Az reads complete before overwrite
    #pragma unroll
    for (int m = 0; m < 4; ++m) {
      int c = wr * 64 + m * 16 + lg * 4;
      float b0 = bias2[c + 0], b1v = bias2[c + 1], b2v_ = bias2[c + 2], b3 = bias2[c + 3];
      #pragma unroll
      for (int nn = 0; nn < 4; ++nn) {
        int r = wc * 64 + nn * 16 + ls;
        f16x4 pv = {(f16)fmaxf(acc[m][nn][0] + b0, 0.f),
                    (f16)fmaxf(acc[m][nn][1] + b1v, 0.f),
                    (f16)fmaxf(acc[m][nn][2] + b2v_, 0.f),
                    (f16)fmaxf(acc[m][nn][3] + b3, 0.f)};
        *(f16x4*)((char*)Az + r * 256 + ((((c >> 3)) ^ (r & 7)) << 4) + (c & 7) * 2) = pv;
      }
    }
    __syncthreads();
    f16* out = (f16*)outv;
    int r = t >> 1, half = t & 1;
    int gr = rowBase + r;
    if (gr < n) {
      #pragma unroll
      for (int j = 0; j < 8; ++j) {
        int ch = half * 8 + j;
        f16x8 v = *(const f16x8*)((const char*)Az + r * 256 + ((ch ^ (r & 7)) << 4));
        *(f16x8*)((char*)(out + (size_t)gr * 128) + half * 128 + j * 16) = v;
      }
    }
  }
}

// ---------------- launch ----------------

extern "C" void kernel_launch(void* const* d_in, const int* in_sizes, int n_in,
                              void* d_out, int out_size, void* d_ws, size_t ws_size,
                              hipStream_t stream) {
  const float* x = (const float*)d_in[0];
  const int* ei = (const int*)d_in[1];
  const float* w1[3] = {(const float*)d_in[2], (const float*)d_in[6], (const float*)d_in[10]};
  const float* b1[3] = {(const float*)d_in[3], (const float*)d_in[7], (const float*)d_in[11]};
  const float* w2[3] = {(const float*)d_in[4], (const float*)d_in[8], (const float*)d_in[12]};
  const float* b2[3] = {(const float*)d_in[5], (const float*)d_in[9], (const float*)d_in[13]};
  const float* wout = (const float*)d_in[14];
  const float* bout = (const float*)d_in[15];
  float* out = (float*)d_out;

  char* ws = (char*)d_ws;
  size_t off = 0;
  f16* B0  = (f16*)(ws + off); off += (size_t)N_NODES * 128 * 2;
  f16* B1  = (f16*)(ws + off); off += (size_t)N_NODES * 128 * 2;
  f16* x16 = (f16*)(ws + off); off += (size_t)N_NODES * 128 * 2;
  f16* Wt[6];
  for (int i = 0; i < 6; ++i) { Wt[i] = (f16*)(ws + off); off += 128 * 128 * 2; }
  int* offs    = (int*)(ws + off); off += (size_t)N_NODES * 4;
  int* counts  = (int*)(ws + off); off += (size_t)N_NODES * 4;
  int* cursors = (int*)(ws + off); off += (size_t)N_NODES * 4;
  int* bsums   = (int*)(ws + off); off += 1024;
  int* scur    = (int*)(ws + off); off += 1024;
  int* srcs    = (int*)(ws + off); off += (size_t)N_EDGES * 4;
  int* bsrc    = (int*)(ws + off); off += (size_t)8 * CAP * 4;
  int* bdst    = (int*)(ws + off); off += (size_t)8 * CAP * 4;

  // ---- CSR build: bucket -> hist -> scan -> fill ----
  hipMemsetAsync(counts, 0, (size_t)N_NODES * 4, stream);
  hipMemsetAsync(cursors, 0, (size_t)N_NODES * 4, stream);
  hipMemsetAsync(scur, 0, 1024, stream);
  bucket_cvt_kernel<<<NACH + 3125, 256, 0, stream>>>(ei, bsrc, bdst, scur, x, x16);
  hist2_kernel<<<8 * NHCH, 256, 0, stream>>>(bdst, scur, counts);
  int nb = (N_NODES + 1023) / 1024;  // 98
  scan1_kernel<<<nb, 256, 0, stream>>>(counts, offs, bsums, N_NODES);
  scan2_kernel<<<1, 128, 0, stream>>>(bsums, nb);
  scan3_kernel<<<(N_NODES + 255) / 256, 256, 0, stream>>>(offs, bsums, N_NODES);
  fill2_kernel<<<8 * NHCH, 256, 0, stream>>>(bsrc, bdst, scur, offs, cursors, srcs);

  // ---- weight prep ----
  WPack wp;
  const float* wsrc[6] = {w1[0], w2[0], w1[1], w2[1], w1[2], w2[2]};
  for (int i = 0; i < 6; ++i) { wp.w[i] = wsrc[i]; wp.o[i] = Wt[i]; }
  wprep_all_kernel<<<384, 256, 0, stream>>>(wp);

  int aggGrid = (N_NODES * 16) / 256;    // 6250 (16-lane group per node)
  int lyrGrid = (N_NODES + 127) / 128;   // 782

  // layer 1
  aggregate_kernel<<<aggGrid, 256, 0, stream>>>(x16, offs, counts, srcs, B0, N_NODES);
  layer_kernel<0><<<lyrGrid, 256, 0, stream>>>(B0, Wt[0], Wt[1], b1[0], b2[0], B1, nullptr, nullptr, N_NODES);
  // layer 2
  aggregate_kernel<<<aggGrid, 256, 0, stream>>>(B1, offs, counts, srcs, B0, N_NODES);
  layer_kernel<0><<<lyrGrid, 256, 0, stream>>>(B0, Wt[2], Wt[3], b1[1], b2[1], B1, nullptr, nullptr, N_NODES);
  // layer 3 (+ fused w_out projection)
  aggregate_kernel<<<aggGrid, 256, 0, stream>>>(B1, offs, counts, srcs, B0, N_NODES);
  layer_kernel<1><<<lyrGrid, 256, 0, stream>>>(B0, Wt[4], Wt[5], b1[2], b2[2], out, wout, bout, N_NODES);
}

// Round 8
// 479.589 us; speedup vs baseline: 1.1384x; 1.1384x over previous
//
#include <hip/hip_runtime.h>

#define N_NODES 100000
#define N_EDGES 1600000
#define SSHIFT 11
#define SNODES 2048          // nodes per slice (power of 2)
#define NSLICE 49            // ceil(N_NODES / SNODES)
#define CAP    36864         // per-slice pair capacity (expected 32768 + 22 sigma)
#define ACHUNK 2048          // edges per bucket block
#define NACH   782           // ceil(N_EDGES / ACHUNK)

typedef _Float16 f16;
typedef _Float16 f16x2 __attribute__((ext_vector_type(2)));
typedef _Float16 f16x4 __attribute__((ext_vector_type(4)));
typedef _Float16 f16x8 __attribute__((ext_vector_type(8)));
typedef float f32x4 __attribute__((ext_vector_type(4)));

// ---------------- phase A: bucket edges by dst-slice (int2 pairs) + fused x->fp16 cvt ----------------
__global__ void bucket_cvt_kernel(const int* __restrict__ ei, int2* __restrict__ bpair,
                                  int* __restrict__ scur,
                                  const float* __restrict__ x, f16* __restrict__ x16) {
  __shared__ int lcnt[64];
  __shared__ int lbase[64];
  int b = blockIdx.x;
  if (b < NACH) {
    if (threadIdx.x < 64) lcnt[threadIdx.x] = 0;
    __syncthreads();
    int base = b * ACHUNK;
    int msrc[8], mdst[8], mrank[8], msl[8];
    #pragma unroll
    for (int j = 0; j < 8; ++j) {
      int i = base + j * 256 + threadIdx.x;
      msl[j] = -1;
      if (i < N_EDGES) {
        msrc[j] = ei[i];
        int d = ei[N_EDGES + i];
        mdst[j] = d;
        int sl = d >> SSHIFT;  // 0..48
        msl[j] = sl;
        mrank[j] = atomicAdd(&lcnt[sl], 1);  // LDS atomic
      }
    }
    __syncthreads();
    if (threadIdx.x < NSLICE) lbase[threadIdx.x] = atomicAdd(&scur[threadIdx.x], lcnt[threadIdx.x]);
    __syncthreads();
    #pragma unroll
    for (int j = 0; j < 8; ++j) {
      if (msl[j] >= 0)
        bpair[(size_t)msl[j] * CAP + lbase[msl[j]] + mrank[j]] = make_int2(msrc[j], mdst[j]);
    }
  } else {
    int i = ((b - NACH) * 256 + threadIdx.x) * 16;  // 16 floats/thread
    float4 a0 = *(const float4*)(x + i);
    float4 a1 = *(const float4*)(x + i + 4);
    float4 a2 = *(const float4*)(x + i + 8);
    float4 a3 = *(const float4*)(x + i + 12);
    f16x8 v0 = {(f16)a0.x, (f16)a0.y, (f16)a0.z, (f16)a0.w,
                (f16)a1.x, (f16)a1.y, (f16)a1.z, (f16)a1.w};
    f16x8 v1 = {(f16)a2.x, (f16)a2.y, (f16)a2.z, (f16)a2.w,
                (f16)a3.x, (f16)a3.y, (f16)a3.z, (f16)a3.w};
    *(f16x8*)(x16 + i) = v0;
    *(f16x8*)(x16 + i + 8) = v1;
  }
}

// ---------------- phase B: per-slice CSR via LDS hist + LDS scan + LDS cursors ----------------
// One block per slice. No global atomics. Produces offs[], counts[] (deg), srcs[].
__global__ __launch_bounds__(256)
void csr_slice_kernel(const int2* __restrict__ bpair, const int* __restrict__ scur,
                      int* __restrict__ offs, int* __restrict__ counts,
                      int* __restrict__ srcs) {
  __shared__ int hist[SNODES];   // 8KB: histogram -> cursors
  __shared__ int sb[64];
  __shared__ int sd[256];
  const int s = blockIdx.x;
  const int t = threadIdx.x;
  for (int j = t; j < SNODES; j += 256) hist[j] = 0;
  if (t < NSLICE) sb[t] = scur[t];
  __syncthreads();
  const int cnt = sb[s];
  int base = 0;
  for (int q = 0; q < NSLICE; ++q) base += (q < s) ? sb[q] : 0;  // broadcast LDS reads

  const int2* p = bpair + (size_t)s * CAP;
  // pass 1: histogram
  for (int i = t; i < cnt; i += 256) atomicAdd(&hist[p[i].y & (SNODES - 1)], 1);
  __syncthreads();

  // block exclusive scan over 2048 hist entries (8 per thread)
  int loc[8];
  int lsum = 0;
  const int jb = t * 8;
  #pragma unroll
  for (int k = 0; k < 8; ++k) { loc[k] = hist[jb + k]; lsum += loc[k]; }
  sd[t] = lsum;
  __syncthreads();
  for (int o = 1; o < 256; o <<= 1) {
    int xv = (t >= o) ? sd[t - o] : 0;
    __syncthreads();
    sd[t] += xv;
    __syncthreads();
  }
  int run = sd[t] - lsum;  // exclusive prefix
  #pragma unroll
  for (int k = 0; k < 8; ++k) {
    int node = s * SNODES + jb + k;
    if (node < N_NODES) { offs[node] = base + run; counts[node] = loc[k]; }
    hist[jb + k] = run;  // becomes cursor
    run += loc[k];
  }
  __syncthreads();

  // pass 2: scatter srcs (LDS cursor atomics; contiguous single-owner output region)
  for (int i = t; i < cnt; i += 256) {
    int2 pr = p[i];
    int pos = base + atomicAdd(&hist[pr.y & (SNODES - 1)], 1);
    srcs[pos] = pr.x;
  }
}

// ---------------- weight prep ----------------
// Wt[c*128 + kc*8 + j] = (f16)W[((kc ^ (c&7))*8 + j)*128 + c]
struct WPack { const float* w[6]; f16* o[6]; };
__global__ void wprep_all_kernel(WPack p) {
  int wi = blockIdx.x >> 6;
  int t = (blockIdx.x & 63) * 256 + threadIdx.x;
  int c = t >> 7;
  int i = t & 127;
  int kc = i >> 3, j = i & 7;
  int k = ((kc ^ (c & 7)) << 3) + j;
  p.o[wi][t] = (f16)p.w[wi][k * 128 + c];
}

// ---------------- aggregation: z[i] = h[i] + sum_{j in N_in(i)} h[j] ----------------
// 16-lane group per node: 16 lanes x f16x8 = full 256B row; 4 nodes per wave.
__global__ void aggregate_kernel(const f16* __restrict__ h, const int* __restrict__ offs,
                                 const int* __restrict__ deg, const int* __restrict__ srcs,
                                 f16* __restrict__ z, int n) {
  int gid = (int)((blockIdx.x * blockDim.x + threadIdx.x) >> 4);
  int gl = threadIdx.x & 15;
  int lb = threadIdx.x & 48;  // group base lane within wave
  if (gid >= n) return;
  int beg = offs[gid];
  int d = deg[gid];
  f16x8 hv = *(const f16x8*)(h + (size_t)gid * 128 + gl * 8);
  float acc[8];
  #pragma unroll
  for (int q = 0; q < 8; ++q) acc[q] = (float)hv[q];
  for (int base = 0; base < d; base += 16) {
    int cnt = min(16, d - base);
    int sv = (base + gl < d) ? srcs[beg + base + gl] : 0;
    int j = 0;
    for (; j + 2 <= cnt; j += 2) {
      int s0 = __shfl(sv, lb + j);
      int s1 = __shfl(sv, lb + j + 1);
      f16x8 a0 = *(const f16x8*)(h + (size_t)s0 * 128 + gl * 8);
      f16x8 a1 = *(const f16x8*)(h + (size_t)s1 * 128 + gl * 8);
      #pragma unroll
      for (int q = 0; q < 8; ++q) acc[q] += (float)a0[q] + (float)a1[q];
    }
    for (; j < cnt; ++j) {
      int s = __shfl(sv, lb + j);
      f16x8 a = *(const f16x8*)(h + (size_t)s * 128 + gl * 8);
      #pragma unroll
      for (int q = 0; q < 8; ++q) acc[q] += (float)a[q];
    }
  }
  f16x8 o;
  #pragma unroll
  for (int q = 0; q < 8; ++q) o[q] = (f16)acc[q];
  *(f16x8*)(z + (size_t)gid * 128 + gl * 8) = o;
}

// ---------------- fused GIN layer (swapped-MFMA): h2 = relu(relu(A@W1+b1)@W2+b2) ----------------
template <int FUSE>
__global__ __launch_bounds__(256, 2)
void layer_kernel(const f16* __restrict__ A, const f16* __restrict__ W1t,
                  const f16* __restrict__ W2t,
                  const float* __restrict__ bias1, const float* __restrict__ bias2,
                  void* __restrict__ outv,
                  const float* __restrict__ wout, const float* __restrict__ bout, int n) {
  __shared__ f16 Az[128 * 128];  // 32KB
  __shared__ f16 Ws[128 * 128];  // 32KB
  const int t = threadIdx.x;
  const int lane = t & 63;
  const int w = t >> 6;
  const int rowBase = blockIdx.x * 128;
  const int wr = w >> 1, wc = w & 1;
  const int ls = lane & 15, lg = lane >> 4;

  // ---- stage A (swizzled) + W1 (linear; pre-swizzled in global) ----
  {
    const char* Ab = (const char*)(A + (size_t)rowBase * 128);
    float4 va[8], v1[8];
    #pragma unroll
    for (int i = 0; i < 8; ++i) {
      int s = w * 512 + i * 64 + lane;
      va[i] = *(const float4*)(Ab + s * 16);
      v1[i] = *(const float4*)((const char*)W1t + s * 16);
    }
    #pragma unroll
    for (int i = 0; i < 8; ++i) {
      int s = w * 512 + i * 64 + lane;
      int r = s >> 4, c = s & 15;
      *(float4*)((char*)Az + r * 256 + ((c ^ (r & 7)) << 4)) = va[i];
      *(float4*)((char*)Ws + s * 16) = v1[i];
    }
  }
  // prefetch W2 into regs (consumed after phase 1)
  float4 v2[8];
  #pragma unroll
  for (int i = 0; i < 8; ++i) {
    int s = w * 512 + i * 64 + lane;
    v2[i] = *(const float4*)((const char*)W2t + s * 16);
  }
  __syncthreads();

  f32x4 acc[4][4];
  #pragma unroll
  for (int m = 0; m < 4; ++m)
    #pragma unroll
    for (int nn = 0; nn < 4; ++nn)
      acc[m][nn] = (f32x4){0.f, 0.f, 0.f, 0.f};

  // ---- phase 1: acc[m][nn] = h1^T fragment ----
  #pragma unroll
  for (int ks = 0; ks < 4; ++ks) {
    f16x8 wf[4], af[4];
    #pragma unroll
    for (int m = 0; m < 4; ++m) {
      int c = wr * 64 + m * 16 + ls;
      int ch = (ks * 4 + lg) ^ (c & 7);
      wf[m] = *(const f16x8*)((const char*)Ws + c * 256 + (ch << 4));
    }
    #pragma unroll
    for (int nn = 0; nn < 4; ++nn) {
      int r = wc * 64 + nn * 16 + ls;
      int ch = (ks * 4 + lg) ^ (r & 7);
      af[nn] = *(const f16x8*)((const char*)Az + r * 256 + (ch << 4));
    }
    #pragma unroll
    for (int m = 0; m < 4; ++m)
      #pragma unroll
      for (int nn = 0; nn < 4; ++nn)
        acc[m][nn] = __builtin_amdgcn_mfma_f32_16x16x32_f16(wf[m], af[nn], acc[m][nn], 0, 0, 0);
  }
  __syncthreads();  // all phase-1 LDS reads complete

  // ---- W2 -> Ws ; h1 (relu+bias) -> Az as packed b64 ----
  #pragma unroll
  for (int i = 0; i < 8; ++i) {
    int s = w * 512 + i * 64 + lane;
    *(float4*)((char*)Ws + s * 16) = v2[i];
  }
  #pragma unroll
  for (int m = 0; m < 4; ++m) {
    int c = wr * 64 + m * 16 + lg * 4;
    float b0 = bias1[c + 0], b1v = bias1[c + 1], b2v_ = bias1[c + 2], b3 = bias1[c + 3];
    #pragma unroll
    for (int nn = 0; nn < 4; ++nn) {
      int r = wc * 64 + nn * 16 + ls;
      f16x4 pv = {(f16)fmaxf(acc[m][nn][0] + b0, 0.f),
                  (f16)fmaxf(acc[m][nn][1] + b1v, 0.f),
                  (f16)fmaxf(acc[m][nn][2] + b2v_, 0.f),
                  (f16)fmaxf(acc[m][nn][3] + b3, 0.f)};
      *(f16x4*)((char*)Az + r * 256 + ((((c >> 3)) ^ (r & 7)) << 4) + (c & 7) * 2) = pv;
    }
  }
  __syncthreads();

  // ---- phase 2: acc[m][nn] = h2^T fragment ----
  #pragma unroll
  for (int m = 0; m < 4; ++m)
    #pragma unroll
    for (int nn = 0; nn < 4; ++nn)
      acc[m][nn] = (f32x4){0.f, 0.f, 0.f, 0.f};
  #pragma unroll
  for (int ks = 0; ks < 4; ++ks) {
    f16x8 wf[4], hf[4];
    #pragma unroll
    for (int m = 0; m < 4; ++m) {
      int c = wr * 64 + m * 16 + ls;
      int ch = (ks * 4 + lg) ^ (c & 7);
      wf[m] = *(const f16x8*)((const char*)Ws + c * 256 + (ch << 4));
    }
    #pragma unroll
    for (int nn = 0; nn < 4; ++nn) {
      int r = wc * 64 + nn * 16 + ls;
      int ch = (ks * 4 + lg) ^ (r & 7);
      hf[nn] = *(const f16x8*)((const char*)Az + r * 256 + (ch << 4));
    }
    #pragma unroll
    for (int m = 0; m < 4; ++m)
      #pragma unroll
      for (int nn = 0; nn < 4; ++nn)
        acc[m][nn] = __builtin_amdgcn_mfma_f32_16x16x32_f16(wf[m], hf[nn], acc[m][nn], 0, 0, 0);
  }

  if (FUSE) {
    float s_[4] = {0.f, 0.f, 0.f, 0.f};
    #pragma unroll
    for (int m = 0; m < 4; ++m) {
      int c = wr * 64 + m * 16 + lg * 4;
      float bb[4], wv[4];
      #pragma unroll
      for (int i = 0; i < 4; ++i) { bb[i] = bias2[c + i]; wv[i] = wout[c + i]; }
      #pragma unroll
      for (int nn = 0; nn < 4; ++nn)
        #pragma unroll
        for (int i = 0; i < 4; ++i)
          s_[nn] += fmaxf(acc[m][nn][i] + bb[i], 0.f) * wv[i];
    }
    #pragma unroll
    for (int nn = 0; nn < 4; ++nn) {
      s_[nn] += __shfl_xor(s_[nn], 16);
      s_[nn] += __shfl_xor(s_[nn], 32);
    }
    __syncthreads();
    float* red = (float*)Az;  // [128][2]
    if (lg == 0) {
      #pragma unroll
      for (int nn = 0; nn < 4; ++nn) red[(wc * 64 + nn * 16 + ls) * 2 + wr] = s_[nn];
    }
    __syncthreads();
    if (t < 128) {
      int gr = rowBase + t;
      if (gr < n) ((float*)outv)[gr] = red[t * 2] + red[t * 2 + 1] + bout[0];
    }
  } else {
    __syncthreads();  // phase-2 Az reads complete before overwrite
    #pragma unroll
    for (int m = 0; m < 4; ++m) {
      int c = wr * 64 + m * 16 + lg * 4;
      float b0 = bias2[c + 0], b1v = bias2[c + 1], b2v_ = bias2[c + 2], b3 = bias2[c + 3];
      #pragma unroll
      for (int nn = 0; nn < 4; ++nn) {
        int r = wc * 64 + nn * 16 + ls;
        f16x4 pv = {(f16)fmaxf(acc[m][nn][0] + b0, 0.f),
                    (f16)fmaxf(acc[m][nn][1] + b1v, 0.f),
                    (f16)fmaxf(acc[m][nn][2] + b2v_, 0.f),
                    (f16)fmaxf(acc[m][nn][3] + b3, 0.f)};
        *(f16x4*)((char*)Az + r * 256 + ((((c >> 3)) ^ (r & 7)) << 4) + (c & 7) * 2) = pv;
      }
    }
    __syncthreads();
    f16* out = (f16*)outv;
    int r = t >> 1, half = t & 1;
    int gr = rowBase + r;
    if (gr < n) {
      #pragma unroll
      for (int j = 0; j < 8; ++j) {
        int ch = half * 8 + j;
        f16x8 v = *(const f16x8*)((const char*)Az + r * 256 + ((ch ^ (r & 7)) << 4));
        *(f16x8*)((char*)(out + (size_t)gr * 128) + half * 128 + j * 16) = v;
      }
    }
  }
}

// ---------------- launch ----------------

extern "C" void kernel_launch(void* const* d_in, const int* in_sizes, int n_in,
                              void* d_out, int out_size, void* d_ws, size_t ws_size,
                              hipStream_t stream) {
  const float* x = (const float*)d_in[0];
  const int* ei = (const int*)d_in[1];
  const float* w1[3] = {(const float*)d_in[2], (const float*)d_in[6], (const float*)d_in[10]};
  const float* b1[3] = {(const float*)d_in[3], (const float*)d_in[7], (const float*)d_in[11]};
  const float* w2[3] = {(const float*)d_in[4], (const float*)d_in[8], (const float*)d_in[12]};
  const float* b2[3] = {(const float*)d_in[5], (const float*)d_in[9], (const float*)d_in[13]};
  const float* wout = (const float*)d_in[14];
  const float* bout = (const float*)d_in[15];
  float* out = (float*)d_out;

  char* ws = (char*)d_ws;
  size_t off = 0;
  f16* B0  = (f16*)(ws + off); off += (size_t)N_NODES * 128 * 2;
  f16* B1  = (f16*)(ws + off); off += (size_t)N_NODES * 128 * 2;
  f16* x16 = (f16*)(ws + off); off += (size_t)N_NODES * 128 * 2;
  f16* Wt[6];
  for (int i = 0; i < 6; ++i) { Wt[i] = (f16*)(ws + off); off += 128 * 128 * 2; }
  int* offs   = (int*)(ws + off); off += (size_t)N_NODES * 4;
  int* counts = (int*)(ws + off); off += (size_t)N_NODES * 4;
  int* scur   = (int*)(ws + off); off += 1024;
  int* srcs   = (int*)(ws + off); off += (size_t)N_EDGES * 4;
  int2* bpair = (int2*)(ws + off); off += (size_t)NSLICE * CAP * 8;

  // ---- CSR build: bucket -> per-slice LDS CSR (no global atomics in hist/fill) ----
  hipMemsetAsync(scur, 0, 1024, stream);
  bucket_cvt_kernel<<<NACH + 3125, 256, 0, stream>>>(ei, bpair, scur, x, x16);
  csr_slice_kernel<<<NSLICE, 256, 0, stream>>>(bpair, scur, offs, counts, srcs);

  // ---- weight prep ----
  WPack wp;
  const float* wsrc[6] = {w1[0], w2[0], w1[1], w2[1], w1[2], w2[2]};
  for (int i = 0; i < 6; ++i) { wp.w[i] = wsrc[i]; wp.o[i] = Wt[i]; }
  wprep_all_kernel<<<384, 256, 0, stream>>>(wp);

  int aggGrid = (N_NODES * 16) / 256;    // 6250 (16-lane group per node)
  int lyrGrid = (N_NODES + 127) / 128;   // 782

  // layer 1
  aggregate_kernel<<<aggGrid, 256, 0, stream>>>(x16, offs, counts, srcs, B0, N_NODES);
  layer_kernel<0><<<lyrGrid, 256, 0, stream>>>(B0, Wt[0], Wt[1], b1[0], b2[0], B1, nullptr, nullptr, N_NODES);
  // layer 2
  aggregate_kernel<<<aggGrid, 256, 0, stream>>>(B1, offs, counts, srcs, B0, N_NODES);
  layer_kernel<0><<<lyrGrid, 256, 0, stream>>>(B0, Wt[2], Wt[3], b1[1], b2[1], B1, nullptr, nullptr, N_NODES);
  // layer 3 (+ fused w_out projection)
  aggregate_kernel<<<aggGrid, 256, 0, stream>>>(B1, offs, counts, srcs, B0, N_NODES);
  layer_kernel<1><<<lyrGrid, 256, 0, stream>>>(B0, Wt[4], Wt[5], b1[2], b2[2], out, wout, bout, N_NODES);
}

// Round 10
// 421.415 us; speedup vs baseline: 1.2956x; 1.1380x over previous
//
#include <hip/hip_runtime.h>

#define N_NODES 100000
#define N_EDGES 1600000
#define SSHIFT 10
#define SNODES 1024          // nodes per slice (power of 2)
#define NSLICE 98            // ceil(N_NODES / SNODES)
#define CAP    18432         // per-slice pair capacity (expected 16327 + ~16 sigma)
#define ACHUNK 2048          // edges per bucket block
#define NACH   782           // ceil(N_EDGES / ACHUNK)
#define NWPREP 384           // wprep blocks

typedef _Float16 f16;
typedef _Float16 f16x2 __attribute__((ext_vector_type(2)));
typedef _Float16 f16x4 __attribute__((ext_vector_type(4)));
typedef _Float16 f16x8 __attribute__((ext_vector_type(8)));
typedef float f32x4 __attribute__((ext_vector_type(4)));

struct WPack { const float* w[6]; f16* o[6]; };

// ---------------- phase A: bucket by dst-slice + wprep + x->fp16 cvt (one launch) ----------------
__global__ void bucket_cvt_kernel(const int* __restrict__ ei, int2* __restrict__ bpair,
                                  int* __restrict__ scur, WPack p,
                                  const float* __restrict__ x, f16* __restrict__ x16) {
  __shared__ int lcnt[NSLICE];
  __shared__ int lbase[NSLICE];
  int b = blockIdx.x;
  if (b < NACH) {
    if (threadIdx.x < NSLICE) lcnt[threadIdx.x] = 0;
    __syncthreads();
    int base = b * ACHUNK;
    int msrc[8], mdst[8], mrank[8], msl[8];
    #pragma unroll
    for (int j = 0; j < 8; ++j) {
      int i = base + j * 256 + threadIdx.x;
      msl[j] = -1;
      if (i < N_EDGES) {
        msrc[j] = ei[i];
        int d = ei[N_EDGES + i];
        mdst[j] = d;
        int sl = d >> SSHIFT;  // 0..97
        msl[j] = sl;
        mrank[j] = atomicAdd(&lcnt[sl], 1);  // LDS atomic
      }
    }
    __syncthreads();
    if (threadIdx.x < NSLICE) lbase[threadIdx.x] = atomicAdd(&scur[threadIdx.x], lcnt[threadIdx.x]);
    __syncthreads();
    #pragma unroll
    for (int j = 0; j < 8; ++j) {
      if (msl[j] >= 0)
        bpair[(size_t)msl[j] * CAP + lbase[msl[j]] + mrank[j]] = make_int2(msrc[j], mdst[j]);
    }
  } else if (b < NACH + NWPREP) {
    int bb = b - NACH;
    int wi = bb >> 6;
    int t = (bb & 63) * 256 + threadIdx.x;  // 0..16383
    int c = t >> 7;
    int i = t & 127;
    int kc = i >> 3, j = i & 7;
    int k = ((kc ^ (c & 7)) << 3) + j;
    p.o[wi][t] = (f16)p.w[wi][k * 128 + c];
  } else {
    int i = ((b - NACH - NWPREP) * 256 + threadIdx.x) * 16;  // 16 floats/thread
    float4 a0 = *(const float4*)(x + i);
    float4 a1 = *(const float4*)(x + i + 4);
    float4 a2 = *(const float4*)(x + i + 8);
    float4 a3 = *(const float4*)(x + i + 12);
    f16x8 v0 = {(f16)a0.x, (f16)a0.y, (f16)a0.z, (f16)a0.w,
                (f16)a1.x, (f16)a1.y, (f16)a1.z, (f16)a1.w};
    f16x8 v1 = {(f16)a2.x, (f16)a2.y, (f16)a2.z, (f16)a2.w,
                (f16)a3.x, (f16)a3.y, (f16)a3.z, (f16)a3.w};
    *(f16x8*)(x16 + i) = v0;
    *(f16x8*)(x16 + i + 8) = v1;
  }
}

// ---------------- phase B: per-slice CSR via LDS hist + scan + cursors (1024 thr) ----------------
__global__ __launch_bounds__(1024)
void csr_slice_kernel(const int2* __restrict__ bpair, const int* __restrict__ scur,
                      int* __restrict__ offs, int* __restrict__ counts,
                      int* __restrict__ srcs) {
  __shared__ int hist[SNODES];   // 4KB: histogram -> exclusive prefix -> cursors
  __shared__ int sb[128];
  __shared__ int sd[1024];
  const int s = blockIdx.x;
  const int t = threadIdx.x;
  if (t < SNODES) hist[t] = 0;
  if (t < NSLICE) sb[t] = scur[t];
  __syncthreads();
  const int cnt = sb[s];
  int base = 0;
  for (int q = 0; q < NSLICE; ++q) base += (q < s) ? sb[q] : 0;  // broadcast LDS reads

  const int2* p = bpair + (size_t)s * CAP;
  // pass 1: histogram
  for (int i = t; i < cnt; i += 1024) atomicAdd(&hist[p[i].y & (SNODES - 1)], 1);
  __syncthreads();

  // block exclusive scan over 1024 hist entries (1 per thread)
  int loc = (t < SNODES) ? hist[t] : 0;
  sd[t] = loc;
  __syncthreads();
  for (int o = 1; o < 1024; o <<= 1) {
    int xv = (t >= o) ? sd[t - o] : 0;
    __syncthreads();
    sd[t] += xv;
    __syncthreads();
  }
  int run = sd[t] - loc;  // exclusive prefix
  if (t < SNODES) {
    int node = s * SNODES + t;
    if (node < N_NODES) { offs[node] = base + run; counts[node] = loc; }
    hist[t] = run;  // becomes cursor
  }
  __syncthreads();

  // pass 2: scatter srcs (LDS cursor atomics; contiguous single-owner output region)
  for (int i = t; i < cnt; i += 1024) {
    int2 pr = p[i];
    int pos = base + atomicAdd(&hist[pr.y & (SNODES - 1)], 1);
    srcs[pos] = pr.x;
  }
}

// ---------------- aggregation: z[i] = h[i] + sum_{j in N_in(i)} h[j] ----------------
// 16-lane group per node: 16 lanes x f16x8 = full 256B row; 4 nodes per wave.
__global__ void aggregate_kernel(const f16* __restrict__ h, const int* __restrict__ offs,
                                 const int* __restrict__ deg, const int* __restrict__ srcs,
                                 f16* __restrict__ z, int n) {
  int gid = (int)((blockIdx.x * blockDim.x + threadIdx.x) >> 4);
  int gl = threadIdx.x & 15;
  int lb = threadIdx.x & 48;  // group base lane within wave
  if (gid >= n) return;
  int beg = offs[gid];
  int d = deg[gid];
  f16x8 hv = *(const f16x8*)(h + (size_t)gid * 128 + gl * 8);
  float acc[8];
  #pragma unroll
  for (int q = 0; q < 8; ++q) acc[q] = (float)hv[q];
  for (int base = 0; base < d; base += 16) {
    int cnt = min(16, d - base);
    int sv = (base + gl < d) ? srcs[beg + base + gl] : 0;
    int j = 0;
    for (; j + 2 <= cnt; j += 2) {
      int s0 = __shfl(sv, lb + j);
      int s1 = __shfl(sv, lb + j + 1);
      f16x8 a0 = *(const f16x8*)(h + (size_t)s0 * 128 + gl * 8);
      f16x8 a1 = *(const f16x8*)(h + (size_t)s1 * 128 + gl * 8);
      #pragma unroll
      for (int q = 0; q < 8; ++q) acc[q] += (float)a0[q] + (float)a1[q];
    }
    for (; j < cnt; ++j) {
      int s = __shfl(sv, lb + j);
      f16x8 a = *(const f16x8*)(h + (size_t)s * 128 + gl * 8);
      #pragma unroll
      for (int q = 0; q < 8; ++q) acc[q] += (float)a[q];
    }
  }
  f16x8 o;
  #pragma unroll
  for (int q = 0; q < 8; ++q) o[q] = (f16)acc[q];
  *(f16x8*)(z + (size_t)gid * 128 + gl * 8) = o;
}

// ---------------- fused GIN layer (swapped-MFMA): h2 = relu(relu(A@W1+b1)@W2+b2) ----------------
template <int FUSE>
__global__ __launch_bounds__(256, 2)
void layer_kernel(const f16* __restrict__ A, const f16* __restrict__ W1t,
                  const f16* __restrict__ W2t,
                  const float* __restrict__ bias1, const float* __restrict__ bias2,
                  void* __restrict__ outv,
                  const float* __restrict__ wout, const float* __restrict__ bout, int n) {
  __shared__ f16 Az[128 * 128];  // 32KB
  __shared__ f16 Ws[128 * 128];  // 32KB
  const int t = threadIdx.x;
  const int lane = t & 63;
  const int w = t >> 6;
  const int rowBase = blockIdx.x * 128;
  const int wr = w >> 1, wc = w & 1;
  const int ls = lane & 15, lg = lane >> 4;

  // ---- stage A (swizzled) + W1 (linear; pre-swizzled in global) ----
  {
    const char* Ab = (const char*)(A + (size_t)rowBase * 128);
    float4 va[8], v1[8];
    #pragma unroll
    for (int i = 0; i < 8; ++i) {
      int s = w * 512 + i * 64 + lane;
      va[i] = *(const float4*)(Ab + s * 16);
      v1[i] = *(const float4*)((const char*)W1t + s * 16);
    }
    #pragma unroll
    for (int i = 0; i < 8; ++i) {
      int s = w * 512 + i * 64 + lane;
      int r = s >> 4, c = s & 15;
      *(float4*)((char*)Az + r * 256 + ((c ^ (r & 7)) << 4)) = va[i];
      *(float4*)((char*)Ws + s * 16) = v1[i];
    }
  }
  // prefetch W2 into regs (consumed after phase 1)
  float4 v2[8];
  #pragma unroll
  for (int i = 0; i < 8; ++i) {
    int s = w * 512 + i * 64 + lane;
    v2[i] = *(const float4*)((const char*)W2t + s * 16);
  }
  __syncthreads();

  f32x4 acc[4][4];
  #pragma unroll
  for (int m = 0; m < 4; ++m)
    #pragma unroll
    for (int nn = 0; nn < 4; ++nn)
      acc[m][nn] = (f32x4){0.f, 0.f, 0.f, 0.f};

  // ---- phase 1: acc[m][nn] = h1^T fragment ----
  #pragma unroll
  for (int ks = 0; ks < 4; ++ks) {
    f16x8 wf[4], af[4];
    #pragma unroll
    for (int m = 0; m < 4; ++m) {
      int c = wr * 64 + m * 16 + ls;
      int ch = (ks * 4 + lg) ^ (c & 7);
      wf[m] = *(const f16x8*)((const char*)Ws + c * 256 + (ch << 4));
    }
    #pragma unroll
    for (int nn = 0; nn < 4; ++nn) {
      int r = wc * 64 + nn * 16 + ls;
      int ch = (ks * 4 + lg) ^ (r & 7);
      af[nn] = *(const f16x8*)((const char*)Az + r * 256 + (ch << 4));
    }
    #pragma unroll
    for (int m = 0; m < 4; ++m)
      #pragma unroll
      for (int nn = 0; nn < 4; ++nn)
        acc[m][nn] = __builtin_amdgcn_mfma_f32_16x16x32_f16(wf[m], af[nn], acc[m][nn], 0, 0, 0);
  }
  __syncthreads();  // all phase-1 LDS reads complete

  // ---- W2 -> Ws ; h1 (relu+bias) -> Az as packed b64 ----
  #pragma unroll
  for (int i = 0; i < 8; ++i) {
    int s = w * 512 + i * 64 + lane;
    *(float4*)((char*)Ws + s * 16) = v2[i];
  }
  #pragma unroll
  for (int m = 0; m < 4; ++m) {
    int c = wr * 64 + m * 16 + lg * 4;
    float b0 = bias1[c + 0], b1v = bias1[c + 1], b2v_ = bias1[c + 2], b3 = bias1[c + 3];
    #pragma unroll
    for (int nn = 0; nn < 4; ++nn) {
      int r = wc * 64 + nn * 16 + ls;
      f16x4 pv = {(f16)fmaxf(acc[m][nn][0] + b0, 0.f),
                  (f16)fmaxf(acc[m][nn][1] + b1v, 0.f),
                  (f16)fmaxf(acc[m][nn][2] + b2v_, 0.f),
                  (f16)fmaxf(acc[m][nn][3] + b3, 0.f)};
      *(f16x4*)((char*)Az + r * 256 + ((((c >> 3)) ^ (r & 7)) << 4) + (c & 7) * 2) = pv;
    }
  }
  __syncthreads();

  // ---- phase 2: acc[m][nn] = h2^T fragment ----
  #pragma unroll
  for (int m = 0; m < 4; ++m)
    #pragma unroll
    for (int nn = 0; nn < 4; ++nn)
      acc[m][nn] = (f32x4){0.f, 0.f, 0.f, 0.f};
  #pragma unroll
  for (int ks = 0; ks < 4; ++ks) {
    f16x8 wf[4], hf[4];
    #pragma unroll
    for (int m = 0; m < 4; ++m) {
      int c = wr * 64 + m * 16 + ls;
      int ch = (ks * 4 + lg) ^ (c & 7);
      wf[m] = *(const f16x8*)((const char*)Ws + c * 256 + (ch << 4));
    }
    #pragma unroll
    for (int nn = 0; nn < 4; ++nn) {
      int r = wc * 64 + nn * 16 + ls;
      int ch = (ks * 4 + lg) ^ (r & 7);
      hf[nn] = *(const f16x8*)((const char*)Az + r * 256 + (ch << 4));
    }
    #pragma unroll
    for (int m = 0; m < 4; ++m)
      #pragma unroll
      for (int nn = 0; nn < 4; ++nn)
        acc[m][nn] = __builtin_amdgcn_mfma_f32_16x16x32_f16(wf[m], hf[nn], acc[m][nn], 0, 0, 0);
  }

  if (FUSE) {
    float s_[4] = {0.f, 0.f, 0.f, 0.f};
    #pragma unroll
    for (int m = 0; m < 4; ++m) {
      int c = wr * 64 + m * 16 + lg * 4;
      float bb[4], wv[4];
      #pragma unroll
      for (int i = 0; i < 4; ++i) { bb[i] = bias2[c + i]; wv[i] = wout[c + i]; }
      #pragma unroll
      for (int nn = 0; nn < 4; ++nn)
        #pragma unroll
        for (int i = 0; i < 4; ++i)
          s_[nn] += fmaxf(acc[m][nn][i] + bb[i], 0.f) * wv[i];
    }
    #pragma unroll
    for (int nn = 0; nn < 4; ++nn) {
      s_[nn] += __shfl_xor(s_[nn], 16);
      s_[nn] += __shfl_xor(s_[nn], 32);
    }
    __syncthreads();
    float* red = (float*)Az;  // [128][2]
    if (lg == 0) {
      #pragma unroll
      for (int nn = 0; nn < 4; ++nn) red[(wc * 64 + nn * 16 + ls) * 2 + wr] = s_[nn];
    }
    __syncthreads();
    if (t < 128) {
      int gr = rowBase + t;
      if (gr < n) ((float*)outv)[gr] = red[t * 2] + red[t * 2 + 1] + bout[0];
    }
  } else {
    __syncthreads();  // phase-2 Az reads complete before overwrite
    #pragma unroll
    for (int m = 0; m < 4; ++m) {
      int c = wr * 64 + m * 16 + lg * 4;
      float b0 = bias2[c + 0], b1v = bias2[c + 1], b2v_ = bias2[c + 2], b3 = bias2[c + 3];
      #pragma unroll
      for (int nn = 0; nn < 4; ++nn) {
        int r = wc * 64 + nn * 16 + ls;
        f16x4 pv = {(f16)fmaxf(acc[m][nn][0] + b0, 0.f),
                    (f16)fmaxf(acc[m][nn][1] + b1v, 0.f),
                    (f16)fmaxf(acc[m][nn][2] + b2v_, 0.f),
                    (f16)fmaxf(acc[m][nn][3] + b3, 0.f)};
        *(f16x4*)((char*)Az + r * 256 + ((((c >> 3)) ^ (r & 7)) << 4) + (c & 7) * 2) = pv;
      }
    }
    __syncthreads();
    f16* out = (f16*)outv;
    int r = t >> 1, half = t & 1;
    int gr = rowBase + r;
    if (gr < n) {
      #pragma unroll
      for (int j = 0; j < 8; ++j) {
        int ch = half * 8 + j;
        f16x8 v = *(const f16x8*)((const char*)Az + r * 256 + ((ch ^ (r & 7)) << 4));
        *(f16x8*)((char*)(out + (size_t)gr * 128) + half * 128 + j * 16) = v;
      }
    }
  }
}

// ---------------- launch ----------------

extern "C" void kernel_launch(void* const* d_in, const int* in_sizes, int n_in,
                              void* d_out, int out_size, void* d_ws, size_t ws_size,
                              hipStream_t stream) {
  const float* x = (const float*)d_in[0];
  const int* ei = (const int*)d_in[1];
  const float* w1[3] = {(const float*)d_in[2], (const float*)d_in[6], (const float*)d_in[10]};
  const float* b1[3] = {(const float*)d_in[3], (const float*)d_in[7], (const float*)d_in[11]};
  const float* w2[3] = {(const float*)d_in[4], (const float*)d_in[8], (const float*)d_in[12]};
  const float* b2[3] = {(const float*)d_in[5], (const float*)d_in[9], (const float*)d_in[13]};
  const float* wout = (const float*)d_in[14];
  const float* bout = (const float*)d_in[15];
  float* out = (float*)d_out;

  char* ws = (char*)d_ws;
  size_t off = 0;
  f16* B0  = (f16*)(ws + off); off += (size_t)N_NODES * 128 * 2;
  f16* B1  = (f16*)(ws + off); off += (size_t)N_NODES * 128 * 2;
  f16* x16 = (f16*)(ws + off); off += (size_t)N_NODES * 128 * 2;
  f16* Wt[6];
  for (int i = 0; i < 6; ++i) { Wt[i] = (f16*)(ws + off); off += 128 * 128 * 2; }
  int* offs   = (int*)(ws + off); off += (size_t)N_NODES * 4;
  int* counts = (int*)(ws + off); off += (size_t)N_NODES * 4;
  int* scur   = (int*)(ws + off); off += 1024;
  int* srcs   = (int*)(ws + off); off += (size_t)N_EDGES * 4;
  int2* bpair = (int2*)(ws + off); off += (size_t)NSLICE * CAP * 8;

  // ---- CSR build: bucket(+wprep+cvt) -> per-slice LDS CSR ----
  hipMemsetAsync(scur, 0, 1024, stream);
  WPack wp;
  const float* wsrc[6] = {w1[0], w2[0], w1[1], w2[1], w1[2], w2[2]};
  for (int i = 0; i < 6; ++i) { wp.w[i] = wsrc[i]; wp.o[i] = Wt[i]; }
  bucket_cvt_kernel<<<NACH + NWPREP + 3125, 256, 0, stream>>>(ei, bpair, scur, wp, x, x16);
  csr_slice_kernel<<<NSLICE, 1024, 0, stream>>>(bpair, scur, offs, counts, srcs);

  int aggGrid = (N_NODES * 16) / 256;    // 6250 (16-lane group per node)
  int lyrGrid = (N_NODES + 127) / 128;   // 782

  // layer 1
  aggregate_kernel<<<aggGrid, 256, 0, stream>>>(x16, offs, counts, srcs, B0, N_NODES);
  layer_kernel<0><<<lyrGrid, 256, 0, stream>>>(B0, Wt[0], Wt[1], b1[0], b2[0], B1, nullptr, nullptr, N_NODES);
  // layer 2
  aggregate_kernel<<<aggGrid, 256, 0, stream>>>(B1, offs, counts, srcs, B0, N_NODES);
  layer_kernel<0><<<lyrGrid, 256, 0, stream>>>(B0, Wt[2], Wt[3], b1[1], b2[1], B1, nullptr, nullptr, N_NODES);
  // layer 3 (+ fused w_out projection)
  aggregate_kernel<<<aggGrid, 256, 0, stream>>>(B1, offs, counts, srcs, B0, N_NODES);
  layer_kernel<1><<<lyrGrid, 256, 0, stream>>>(B0, Wt[4], Wt[5], b1[2], b2[2], out, wout, bout, N_NODES);
}

// Round 11
// 394.807 us; speedup vs baseline: 1.3829x; 1.0674x over previous
//
#include <hip/hip_runtime.h>

#define N_NODES 100000
#define N_EDGES 1600000
#define SSHIFT 10
#define SNODES 1024          // nodes per slice (power of 2)
#define NSLICE 98            // ceil(N_NODES / SNODES)
#define CAP    18432         // per-slice pair capacity (expected 16327 + ~16 sigma)
#define ACHUNK 2048          // edges per bucket block
#define NACH   782           // ceil(N_EDGES / ACHUNK)
#define NWPREP 384           // wprep blocks
#define NCVT   6250          // cvt blocks (N_NODES*16 chunks / 256)

typedef _Float16 f16;
typedef _Float16 f16x2 __attribute__((ext_vector_type(2)));
typedef _Float16 f16x4 __attribute__((ext_vector_type(4)));
typedef _Float16 f16x8 __attribute__((ext_vector_type(8)));
typedef float f32x4 __attribute__((ext_vector_type(4)));

struct WPack { const float* w[6]; f16* o[6]; };

// All feature buffers (x16, B0, B1) are stored CHUNK-SWIZZLED per row:
// logical 16B-chunk c of row r lives at byte offset (c ^ (r & 7)) * 16 within the row.
// This lets layer_kernel stage A with linear global_load_lds.

// ---------------- phase A: bucket by dst-slice + wprep + x->fp16 swizzled cvt ----------------
__global__ void bucket_cvt_kernel(const int* __restrict__ ei, int2* __restrict__ bpair,
                                  int* __restrict__ scur, WPack p,
                                  const float* __restrict__ x, f16* __restrict__ x16) {
  __shared__ int lcnt[NSLICE];
  __shared__ int lbase[NSLICE];
  int b = blockIdx.x;
  if (b < NACH) {
    if (threadIdx.x < NSLICE) lcnt[threadIdx.x] = 0;
    __syncthreads();
    int base = b * ACHUNK;
    int msrc[8], mdst[8], mrank[8], msl[8];
    #pragma unroll
    for (int j = 0; j < 8; ++j) {
      int i = base + j * 256 + threadIdx.x;
      msl[j] = -1;
      if (i < N_EDGES) {
        msrc[j] = ei[i];
        int d = ei[N_EDGES + i];
        mdst[j] = d;
        int sl = d >> SSHIFT;  // 0..97
        msl[j] = sl;
        mrank[j] = atomicAdd(&lcnt[sl], 1);  // LDS atomic
      }
    }
    __syncthreads();
    if (threadIdx.x < NSLICE) lbase[threadIdx.x] = atomicAdd(&scur[threadIdx.x], lcnt[threadIdx.x]);
    __syncthreads();
    #pragma unroll
    for (int j = 0; j < 8; ++j) {
      if (msl[j] >= 0)
        bpair[(size_t)msl[j] * CAP + lbase[msl[j]] + mrank[j]] = make_int2(msrc[j], mdst[j]);
    }
  } else if (b < NACH + NWPREP) {
    int bb = b - NACH;
    int wi = bb >> 6;
    int t = (bb & 63) * 256 + threadIdx.x;  // 0..16383
    int c = t >> 7;
    int i = t & 127;
    int kc = i >> 3, j = i & 7;
    int k = ((kc ^ (c & 7)) << 3) + j;
    p.o[wi][t] = (f16)p.w[wi][k * 128 + c];
  } else {
    // cvt: one 16B chunk per thread, swizzled write
    int tt = (b - NACH - NWPREP) * 256 + threadIdx.x;  // 0..1599999
    int r = tt >> 4, c = tt & 15;
    const float* xs = x + r * 128 + c * 8;
    float4 a0 = *(const float4*)(xs);
    float4 a1 = *(const float4*)(xs + 4);
    f16x8 v = {(f16)a0.x, (f16)a0.y, (f16)a0.z, (f16)a0.w,
               (f16)a1.x, (f16)a1.y, (f16)a1.z, (f16)a1.w};
    *(f16x8*)(x16 + r * 128 + ((c ^ (r & 7)) << 3)) = v;
  }
}

// ---------------- phase B: per-slice CSR via LDS hist + scan + cursors (1024 thr) ----------------
__global__ __launch_bounds__(1024)
void csr_slice_kernel(const int2* __restrict__ bpair, const int* __restrict__ scur,
                      int* __restrict__ offs, int* __restrict__ counts,
                      int* __restrict__ srcs) {
  __shared__ int hist[SNODES];   // 4KB: histogram -> exclusive prefix -> cursors
  __shared__ int sb[128];
  __shared__ int sd[1024];
  const int s = blockIdx.x;
  const int t = threadIdx.x;
  if (t < SNODES) hist[t] = 0;
  if (t < NSLICE) sb[t] = scur[t];
  __syncthreads();
  const int cnt = sb[s];
  int base = 0;
  for (int q = 0; q < NSLICE; ++q) base += (q < s) ? sb[q] : 0;  // broadcast LDS reads

  const int2* p = bpair + (size_t)s * CAP;
  // pass 1: histogram
  for (int i = t; i < cnt; i += 1024) atomicAdd(&hist[p[i].y & (SNODES - 1)], 1);
  __syncthreads();

  // block exclusive scan over 1024 hist entries (1 per thread)
  int loc = (t < SNODES) ? hist[t] : 0;
  sd[t] = loc;
  __syncthreads();
  for (int o = 1; o < 1024; o <<= 1) {
    int xv = (t >= o) ? sd[t - o] : 0;
    __syncthreads();
    sd[t] += xv;
    __syncthreads();
  }
  int run = sd[t] - loc;  // exclusive prefix
  if (t < SNODES) {
    int node = s * SNODES + t;
    if (node < N_NODES) { offs[node] = base + run; counts[node] = loc; }
    hist[t] = run;  // becomes cursor
  }
  __syncthreads();

  // pass 2: scatter srcs (LDS cursor atomics; contiguous single-owner output region)
  for (int i = t; i < cnt; i += 1024) {
    int2 pr = p[i];
    int pos = base + atomicAdd(&hist[pr.y & (SNODES - 1)], 1);
    srcs[pos] = pr.x;
  }
}

// ---------------- aggregation: z[i] = h[i] + sum_{j in N_in(i)} h[j]  (swizzled rows) ----------------
// 16-lane group per node; lane gl holds logical chunk gl (reads position gl^(row&7)).
__global__ void aggregate_kernel(const f16* __restrict__ h, const int* __restrict__ offs,
                                 const int* __restrict__ deg, const int* __restrict__ srcs,
                                 f16* __restrict__ z, int n) {
  int gid = (int)((blockIdx.x * blockDim.x + threadIdx.x) >> 4);
  int gl = threadIdx.x & 15;
  int lb = threadIdx.x & 48;  // group base lane within wave
  if (gid >= n) return;
  int beg = offs[gid];
  int d = deg[gid];
  f16x8 hv = *(const f16x8*)(h + (size_t)gid * 128 + ((gl ^ (gid & 7)) << 3));
  float acc[8];
  #pragma unroll
  for (int q = 0; q < 8; ++q) acc[q] = (float)hv[q];
  for (int base = 0; base < d; base += 16) {
    int cnt = min(16, d - base);
    int sv = (base + gl < d) ? srcs[beg + base + gl] : 0;
    int j = 0;
    for (; j + 2 <= cnt; j += 2) {
      int s0 = __shfl(sv, lb + j);
      int s1 = __shfl(sv, lb + j + 1);
      f16x8 a0 = *(const f16x8*)(h + (size_t)s0 * 128 + ((gl ^ (s0 & 7)) << 3));
      f16x8 a1 = *(const f16x8*)(h + (size_t)s1 * 128 + ((gl ^ (s1 & 7)) << 3));
      #pragma unroll
      for (int q = 0; q < 8; ++q) acc[q] += (float)a0[q] + (float)a1[q];
    }
    for (; j < cnt; ++j) {
      int s = __shfl(sv, lb + j);
      f16x8 a = *(const f16x8*)(h + (size_t)s * 128 + ((gl ^ (s & 7)) << 3));
      #pragma unroll
      for (int q = 0; q < 8; ++q) acc[q] += (float)a[q];
    }
  }
  f16x8 o;
  #pragma unroll
  for (int q = 0; q < 8; ++q) o[q] = (f16)acc[q];
  *(f16x8*)(z + (size_t)gid * 128 + ((gl ^ (gid & 7)) << 3)) = o;
}

// ---------------- fused GIN layer, 512 threads (8 waves = 2 row-groups x 4 col-groups) ----------------
// h2 = relu(relu(A@W1+b1)@W2+b2), swapped-MFMA (computes transposed fragments).
// A and W1 staged via global_load_lds (both stored (pre-)swizzled in global -> linear LDS dest).
// W2 global_load_lds'd into Ws after phase-1 barrier (hides under h1 writeback).
template <int FUSE>
__global__ __launch_bounds__(512, 4)
void layer_kernel(const f16* __restrict__ A, const f16* __restrict__ W1t,
                  const f16* __restrict__ W2t,
                  const float* __restrict__ bias1, const float* __restrict__ bias2,
                  void* __restrict__ outv,
                  const float* __restrict__ wout, const float* __restrict__ bout, int n) {
  __shared__ f16 Az[128 * 128];  // 32KB: A -> h1 -> h2 (chunk-swizzled rows)
  __shared__ f16 Ws[128 * 128];  // 32KB: W1 -> W2 (pre-swizzled)
  const int t = threadIdx.x;
  const int lane = t & 63;
  const int w = t >> 6;          // 0..7
  const int rowBase = blockIdx.x * 128;
  const int wr = w >> 2;         // 0..1 : A-row group (64 rows)
  const int wc = w & 3;          // 0..3 : W-col group (32 cols)
  const int ls = lane & 15, lg = lane >> 4;

  // ---- stage A + W1 via global_load_lds (1KB per wave-instr, contiguous source) ----
  {
    const char* Ab = (const char*)A + (size_t)rowBase * 256;
    const char* Wb = (const char*)W1t;
    #pragma unroll
    for (int it = 0; it < 4; ++it) {
      int off = w * 4096 + it * 1024;
      __builtin_amdgcn_global_load_lds(
          (const __attribute__((address_space(1))) void*)(Ab + off + lane * 16),
          (__attribute__((address_space(3))) void*)((char*)Az + off), 16, 0, 0);
      __builtin_amdgcn_global_load_lds(
          (const __attribute__((address_space(1))) void*)(Wb + off + lane * 16),
          (__attribute__((address_space(3))) void*)((char*)Ws + off), 16, 0, 0);
    }
  }
  __syncthreads();  // drains vmcnt

  f32x4 acc[2][4];
  #pragma unroll
  for (int m = 0; m < 2; ++m)
    #pragma unroll
    for (int nn = 0; nn < 4; ++nn)
      acc[m][nn] = (f32x4){0.f, 0.f, 0.f, 0.f};

  // ---- phase 1: acc = h1^T fragments ----
  #pragma unroll
  for (int ks = 0; ks < 4; ++ks) {
    f16x8 wf[2], af[4];
    #pragma unroll
    for (int m = 0; m < 2; ++m) {
      int c = wc * 32 + m * 16 + ls;
      int ch = (ks * 4 + lg) ^ (c & 7);
      wf[m] = *(const f16x8*)((const char*)Ws + c * 256 + (ch << 4));
    }
    #pragma unroll
    for (int nn = 0; nn < 4; ++nn) {
      int r = wr * 64 + nn * 16 + ls;
      int ch = (ks * 4 + lg) ^ (r & 7);
      af[nn] = *(const f16x8*)((const char*)Az + r * 256 + (ch << 4));
    }
    #pragma unroll
    for (int m = 0; m < 2; ++m)
      #pragma unroll
      for (int nn = 0; nn < 4; ++nn)
        acc[m][nn] = __builtin_amdgcn_mfma_f32_16x16x32_f16(wf[m], af[nn], acc[m][nn], 0, 0, 0);
  }
  __syncthreads();  // all phase-1 LDS reads complete

  // ---- W2 -> Ws via global_load_lds (latency hides under h1 writeback) ----
  {
    const char* Wb = (const char*)W2t;
    #pragma unroll
    for (int it = 0; it < 4; ++it) {
      int off = w * 4096 + it * 1024;
      __builtin_amdgcn_global_load_lds(
          (const __attribute__((address_space(1))) void*)(Wb + off + lane * 16),
          (__attribute__((address_space(3))) void*)((char*)Ws + off), 16, 0, 0);
    }
  }
  // ---- h1 (relu+bias) -> Az swizzled, packed b64 ----
  #pragma unroll
  for (int m = 0; m < 2; ++m) {
    int c = wc * 32 + m * 16 + lg * 4;
    float b0 = bias1[c + 0], b1v = bias1[c + 1], b2v_ = bias1[c + 2], b3 = bias1[c + 3];
    #pragma unroll
    for (int nn = 0; nn < 4; ++nn) {
      int r = wr * 64 + nn * 16 + ls;
      f16x4 pv = {(f16)fmaxf(acc[m][nn][0] + b0, 0.f),
                  (f16)fmaxf(acc[m][nn][1] + b1v, 0.f),
                  (f16)fmaxf(acc[m][nn][2] + b2v_, 0.f),
                  (f16)fmaxf(acc[m][nn][3] + b3, 0.f)};
      *(f16x4*)((char*)Az + r * 256 + ((((c >> 3)) ^ (r & 7)) << 4) + (c & 7) * 2) = pv;
    }
  }
  __syncthreads();  // drains W2 vmcnt + h1 lgkm

  // ---- phase 2: acc = h2^T fragments ----
  #pragma unroll
  for (int m = 0; m < 2; ++m)
    #pragma unroll
    for (int nn = 0; nn < 4; ++nn)
      acc[m][nn] = (f32x4){0.f, 0.f, 0.f, 0.f};
  #pragma unroll
  for (int ks = 0; ks < 4; ++ks) {
    f16x8 wf[2], hf[4];
    #pragma unroll
    for (int m = 0; m < 2; ++m) {
      int c = wc * 32 + m * 16 + ls;
      int ch = (ks * 4 + lg) ^ (c & 7);
      wf[m] = *(const f16x8*)((const char*)Ws + c * 256 + (ch << 4));
    }
    #pragma unroll
    for (int nn = 0; nn < 4; ++nn) {
      int r = wr * 64 + nn * 16 + ls;
      int ch = (ks * 4 + lg) ^ (r & 7);
      hf[nn] = *(const f16x8*)((const char*)Az + r * 256 + (ch << 4));
    }
    #pragma unroll
    for (int m = 0; m < 2; ++m)
      #pragma unroll
      for (int nn = 0; nn < 4; ++nn)
        acc[m][nn] = __builtin_amdgcn_mfma_f32_16x16x32_f16(wf[m], hf[nn], acc[m][nn], 0, 0, 0);
  }

  if (FUSE) {
    // out[r] = sum_c relu(h2 + b2)[r][c] * wout[c] + bout
    float s_[4] = {0.f, 0.f, 0.f, 0.f};
    #pragma unroll
    for (int m = 0; m < 2; ++m) {
      int c = wc * 32 + m * 16 + lg * 4;
      float bb[4], wv[4];
      #pragma unroll
      for (int i = 0; i < 4; ++i) { bb[i] = bias2[c + i]; wv[i] = wout[c + i]; }
      #pragma unroll
      for (int nn = 0; nn < 4; ++nn)
        #pragma unroll
        for (int i = 0; i < 4; ++i)
          s_[nn] += fmaxf(acc[m][nn][i] + bb[i], 0.f) * wv[i];
    }
    #pragma unroll
    for (int nn = 0; nn < 4; ++nn) {
      s_[nn] += __shfl_xor(s_[nn], 16);
      s_[nn] += __shfl_xor(s_[nn], 32);
    }
    __syncthreads();  // Az/Ws reads complete
    float* red = (float*)Az;  // [128][4]
    if (lg == 0) {
      #pragma unroll
      for (int nn = 0; nn < 4; ++nn) red[(wr * 64 + nn * 16 + ls) * 4 + wc] = s_[nn];
    }
    __syncthreads();
    if (t < 128) {
      int gr = rowBase + t;
      if (gr < n)
        ((float*)outv)[gr] = red[t * 4] + red[t * 4 + 1] + red[t * 4 + 2] + red[t * 4 + 3] + bout[0];
    }
  } else {
    __syncthreads();  // phase-2 Az reads complete before overwrite
    #pragma unroll
    for (int m = 0; m < 2; ++m) {
      int c = wc * 32 + m * 16 + lg * 4;
      float b0 = bias2[c + 0], b1v = bias2[c + 1], b2v_ = bias2[c + 2], b3 = bias2[c + 3];
      #pragma unroll
      for (int nn = 0; nn < 4; ++nn) {
        int r = wr * 64 + nn * 16 + ls;
        f16x4 pv = {(f16)fmaxf(acc[m][nn][0] + b0, 0.f),
                    (f16)fmaxf(acc[m][nn][1] + b1v, 0.f),
                    (f16)fmaxf(acc[m][nn][2] + b2v_, 0.f),
                    (f16)fmaxf(acc[m][nn][3] + b3, 0.f)};
        *(f16x4*)((char*)Az + r * 256 + ((((c >> 3)) ^ (r & 7)) << 4) + (c & 7) * 2) = pv;
      }
    }
    __syncthreads();
    // linear copy-out: Az layout == swizzled global layout; lane-stride 16B (conflict-free)
    #pragma unroll
    for (int j = 0; j < 4; ++j) {
      int byteoff = t * 16 + j * 8192;
      int r = byteoff >> 8;
      if (rowBase + r < n) {
        f16x8 v = *(const f16x8*)((const char*)Az + byteoff);
        *(f16x8*)((char*)outv + (size_t)rowBase * 256 + byteoff) = v;
      }
    }
  }
}

// ---------------- launch ----------------

extern "C" void kernel_launch(void* const* d_in, const int* in_sizes, int n_in,
                              void* d_out, int out_size, void* d_ws, size_t ws_size,
                              hipStream_t stream) {
  const float* x = (const float*)d_in[0];
  const int* ei = (const int*)d_in[1];
  const float* w1[3] = {(const float*)d_in[2], (const float*)d_in[6], (const float*)d_in[10]};
  const float* b1[3] = {(const float*)d_in[3], (const float*)d_in[7], (const float*)d_in[11]};
  const float* w2[3] = {(const float*)d_in[4], (const float*)d_in[8], (const float*)d_in[12]};
  const float* b2[3] = {(const float*)d_in[5], (const float*)d_in[9], (const float*)d_in[13]};
  const float* wout = (const float*)d_in[14];
  const float* bout = (const float*)d_in[15];
  float* out = (float*)d_out;

  char* ws = (char*)d_ws;
  size_t off = 0;
  f16* B0  = (f16*)(ws + off); off += (size_t)N_NODES * 128 * 2;
  f16* B1  = (f16*)(ws + off); off += (size_t)N_NODES * 128 * 2;
  f16* x16 = (f16*)(ws + off); off += (size_t)N_NODES * 128 * 2;
  f16* Wt[6];
  for (int i = 0; i < 6; ++i) { Wt[i] = (f16*)(ws + off); off += 128 * 128 * 2; }
  int* offs   = (int*)(ws + off); off += (size_t)N_NODES * 4;
  int* counts = (int*)(ws + off); off += (size_t)N_NODES * 4;
  int* scur   = (int*)(ws + off); off += 1024;
  int* srcs   = (int*)(ws + off); off += (size_t)N_EDGES * 4;
  int2* bpair = (int2*)(ws + off); off += (size_t)NSLICE * CAP * 8;

  // ---- CSR build: bucket(+wprep+cvt) -> per-slice LDS CSR ----
  hipMemsetAsync(scur, 0, 1024, stream);
  WPack wp;
  const float* wsrc[6] = {w1[0], w2[0], w1[1], w2[1], w1[2], w2[2]};
  for (int i = 0; i < 6; ++i) { wp.w[i] = wsrc[i]; wp.o[i] = Wt[i]; }
  bucket_cvt_kernel<<<NACH + NWPREP + NCVT, 256, 0, stream>>>(ei, bpair, scur, wp, x, x16);
  csr_slice_kernel<<<NSLICE, 1024, 0, stream>>>(bpair, scur, offs, counts, srcs);

  int aggGrid = (N_NODES * 16) / 256;    // 6250 (16-lane group per node)
  int lyrGrid = (N_NODES + 127) / 128;   // 782

  // layer 1
  aggregate_kernel<<<aggGrid, 256, 0, stream>>>(x16, offs, counts, srcs, B0, N_NODES);
  layer_kernel<0><<<lyrGrid, 512, 0, stream>>>(B0, Wt[0], Wt[1], b1[0], b2[0], B1, nullptr, nullptr, N_NODES);
  // layer 2
  aggregate_kernel<<<aggGrid, 256, 0, stream>>>(B1, offs, counts, srcs, B0, N_NODES);
  layer_kernel<0><<<lyrGrid, 512, 0, stream>>>(B0, Wt[2], Wt[3], b1[1], b2[1], B1, nullptr, nullptr, N_NODES);
  // layer 3 (+ fused w_out projection)
  aggregate_kernel<<<aggGrid, 256, 0, stream>>>(B1, offs, counts, srcs, B0, N_NODES);
  layer_kernel<1><<<lyrGrid, 512, 0, stream>>>(B0, Wt[4], Wt[5], b1[2], b2[2], out, wout, bout, N_NODES);
}